// Round 2
// baseline (488.732 us; speedup 1.0000x reference)
//
#include <hip/hip_runtime.h>
#include <hip/hip_bf16.h>
#include <math.h>

#define MAXO 16

// ---------------------------------------------------------------------------
// m1: IoU over (b, d-chunk): per-default argmax over objects (first-wins),
//     per-object argmax over defaults via packed 64-bit atomicMax
//     key = (iou_bits << 32) | (~d)  -> max iou, tie -> lowest d
// ---------------------------------------------------------------------------
__global__ void m1_kernel(const float* __restrict__ boxes,   // [B,O,4] xy
                          const float* __restrict__ dboxes,  // [D,4] cxcy
                          int*   __restrict__ tcls,          // [B,D] obj idx
                          float* __restrict__ ovl,           // [B,D] best iou
                          unsigned long long* __restrict__ key64, // [B,O]
                          int D, int O, int CH, int chunk) {
    int b = blockIdx.x / CH, c = blockIdx.x % CH;
    int t = threadIdx.x;

    __shared__ float sbox[MAXO][4];
    __shared__ float sarea[MAXO];
    if (t < O) {
        const float* bp = boxes + ((size_t)b * O + t) * 4;
        float x1 = bp[0], y1 = bp[1], x2 = bp[2], y2 = bp[3];
        sbox[t][0] = x1; sbox[t][1] = y1; sbox[t][2] = x2; sbox[t][3] = y2;
        sarea[t] = (x2 - x1) * (y2 - y1);
    }
    __syncthreads();

    float bestv[MAXO];
    int   besti[MAXO];
#pragma unroll
    for (int o = 0; o < MAXO; ++o) { bestv[o] = -1.0f; besti[o] = 0x7fffffff; }

    size_t rowoff = (size_t)b * D;
    int d0 = c * chunk, d1 = min(D, d0 + chunk);

    for (int d = d0 + t; d < d1; d += 256) {
        float4 db = ((const float4*)dboxes)[d];
        float dx1 = db.x - db.z * 0.5f, dy1 = db.y - db.w * 0.5f;
        float dx2 = db.x + db.z * 0.5f, dy2 = db.y + db.w * 0.5f;
        float a2 = (dx2 - dx1) * (dy2 - dy1);
        float mval = -1.0f; int mobj = 0;
#pragma unroll
        for (int o = 0; o < MAXO; ++o) {
            if (o < O) {
                float lx = fmaxf(sbox[o][0], dx1), ly = fmaxf(sbox[o][1], dy1);
                float rx = fminf(sbox[o][2], dx2), ry = fminf(sbox[o][3], dy2);
                float w = fmaxf(rx - lx, 0.0f), h = fmaxf(ry - ly, 0.0f);
                float inter = w * h;
                float iou = inter / (sarea[o] + a2 - inter);
                if (iou > mval) { mval = iou; mobj = o; }   // first-wins over o
                if (iou > bestv[o] || (iou == bestv[o] && d < besti[o])) {
                    bestv[o] = iou; besti[o] = d;           // lowest-d wins
                }
            }
        }
        tcls[rowoff + d] = mobj;
        ovl[rowoff + d]  = mval;
    }

#pragma unroll
    for (int o = 0; o < MAXO; ++o) {
        if (o < O && bestv[o] >= 0.0f) {
            unsigned long long key =
                ((unsigned long long)__float_as_uint(bestv[o]) << 32) |
                (unsigned long long)(0xFFFFFFFFu - (unsigned)besti[o]);
            atomicMax(&key64[(size_t)b * O + o], key);
        }
    }
}

// ---------------------------------------------------------------------------
// m2: sequential last-write-wins override (numpy scatter semantics)
// ---------------------------------------------------------------------------
__global__ void m2_kernel(const unsigned long long* __restrict__ key64,
                          int* __restrict__ tcls, float* __restrict__ ovl,
                          int D, int O, int B) {
    int b = threadIdx.x;
    if (b >= B) return;
    size_t rowoff = (size_t)b * D;
    for (int o = 0; o < O; ++o) {
        unsigned long long key = key64[(size_t)b * O + o];
        int d = (int)(0xFFFFFFFFu - (unsigned)(key & 0xFFFFFFFFull));
        tcls[rowoff + d] = o;
        ovl[rowoff + d]  = 1.0f;
    }
}

// ---------------------------------------------------------------------------
// m3: labels, encode, smooth-L1 for positives; n_pos / npt / loc_sum
// ---------------------------------------------------------------------------
__global__ void m3_kernel(const float* __restrict__ boxes,
                          const int*   __restrict__ labels,
                          const float* __restrict__ dboxes,
                          const float* __restrict__ locs,
                          int*   __restrict__ tcls,
                          const float* __restrict__ ovl,
                          int*   __restrict__ n_pos,
                          double* __restrict__ loc_sum,
                          int*   __restrict__ npt,
                          int D, int O, int CHm) {
    int b = blockIdx.x / CHm, c = blockIdx.x % CHm;
    int t = threadIdx.x;
    int d = c * 256 + t;

    __shared__ float sbox[MAXO][4];
    __shared__ int   slab[MAXO];
    __shared__ double sred[256];
    __shared__ int    sredi[256];
    if (t < O) {
        const float* bp = boxes + ((size_t)b * O + t) * 4;
        sbox[t][0] = bp[0]; sbox[t][1] = bp[1]; sbox[t][2] = bp[2]; sbox[t][3] = bp[3];
        slab[t] = labels[(size_t)b * O + t];
    }
    __syncthreads();

    double acc = 0.0;
    int cnt = 0;
    if (d < D) {
        size_t rowoff = (size_t)b * D;
        int o = tcls[rowoff + d];
        float ov = ovl[rowoff + d];
        int lab = (ov < 0.5f) ? 0 : slab[o];
        tcls[rowoff + d] = lab;
        if (lab != 0) {
            cnt = 1;
            float x1 = sbox[o][0], y1 = sbox[o][1], x2 = sbox[o][2], y2 = sbox[o][3];
            float cx = (x1 + x2) * 0.5f, cy = (y1 + y2) * 0.5f;
            float w = x2 - x1, h = y2 - y1;
            float4 db = ((const float4*)dboxes)[d];
            float g0 = (cx - db.x) / (db.z * 0.1f);
            float g1 = (cy - db.y) / (db.w * 0.1f);
            float g2 = __logf(w / db.z) * 5.0f;
            float g3 = __logf(h / db.w) * 5.0f;
            float4 lp = ((const float4*)locs)[rowoff + d];
            float dd;
            dd = fabsf(lp.x - g0); acc += (dd < 1.0f) ? 0.5f * dd * dd : dd - 0.5f;
            dd = fabsf(lp.y - g1); acc += (dd < 1.0f) ? 0.5f * dd * dd : dd - 0.5f;
            dd = fabsf(lp.z - g2); acc += (dd < 1.0f) ? 0.5f * dd * dd : dd - 0.5f;
            dd = fabsf(lp.w - g3); acc += (dd < 1.0f) ? 0.5f * dd * dd : dd - 0.5f;
        }
    }
    sred[t] = acc; sredi[t] = cnt;
    __syncthreads();
    for (int s = 128; s > 0; s >>= 1) {
        if (t < s) { sred[t] += sred[t + s]; sredi[t] += sredi[t + s]; }
        __syncthreads();
    }
    if (t == 0) {
        if (sredi[0]) { atomicAdd(&n_pos[b], sredi[0]); atomicAdd(npt, sredi[0]); }
        if (sred[0] != 0.0) atomicAdd(loc_sum, sred[0]);
    }
}

// ---------------------------------------------------------------------------
// ce (fast path, C known at compile time): 64-row LDS tiles, 4 threads/row,
// row elements held in registers, quad shfl reduce, hw transcendentals
// ---------------------------------------------------------------------------
template<int CC>
__global__ __launch_bounds__(256) void ce_tile_kernel(
        const float* __restrict__ cls,  // [R,CC]
        const int*   __restrict__ tcls, // [R]
        float* __restrict__ negbuf,     // [R]
        double* __restrict__ pos_sum,   // [1]
        int R) {
    constexpr int TF  = 64 * CC;      // floats per tile
    constexpr int TF4 = TF / 4;       // float4 per tile
    constexpr int PER = (CC + 3) / 4; // elems per thread
    __shared__ __align__(16) float lds[TF];
    int t = threadIdx.x;
    int ntiles = R / 64;
    double acc = 0.0;

    for (int tile = blockIdx.x; tile < ntiles; tile += gridDim.x) {
        const float4* g4 = (const float4*)cls + (size_t)tile * TF4;
#pragma unroll
        for (int i = 0; i < (TF4 + 255) / 256; ++i) {
            int idx = t + i * 256;
            if (idx < TF4) ((float4*)lds)[idx] = g4[idx];
        }
        __syncthreads();

        int rr = t >> 2, p = t & 3;
        int row = tile * 64 + rr;
        const float* Lr = lds + rr * CC;
        int j0 = p * PER;

        float v[PER];
#pragma unroll
        for (int k = 0; k < PER; ++k) {
            int j = j0 + k;
            v[k] = (j < CC) ? Lr[j] : -INFINITY;
        }
        float m = v[0];
#pragma unroll
        for (int k = 1; k < PER; ++k) m = fmaxf(m, v[k]);
        m = fmaxf(m, __shfl_xor(m, 1));
        m = fmaxf(m, __shfl_xor(m, 2));
        float e = 0.0f;
#pragma unroll
        for (int k = 0; k < PER; ++k) e += __expf(v[k] - m); // exp(-inf)=0
        e += __shfl_xor(e, 1);
        e += __shfl_xor(e, 2);

        if (p == 0) {
            int tgt = tcls[row];
            float lt = Lr[tgt];
            float ce = __logf(e) + m - lt;
            ce = fmaxf(ce, 0.0f);
            if (tgt != 0) acc += (double)ce;
            negbuf[row] = (tgt != 0) ? 0.0f : ce;
        }
        __syncthreads();
    }

    // block-reduce acc -> one atomic
    double* sd = (double*)lds;
    sd[t] = acc;
    __syncthreads();
    for (int s = 128; s > 0; s >>= 1) {
        if (t < s) sd[t] += sd[t + s];
        __syncthreads();
    }
    if (t == 0 && sd[0] != 0.0) atomicAdd(pos_sum, sd[0]);
}

// ---------------------------------------------------------------------------
// ce fallback (generic C): wave per row
// ---------------------------------------------------------------------------
__global__ void ce_kernel(const float* __restrict__ cls, const int* __restrict__ tcls,
                          float* __restrict__ negbuf, double* __restrict__ pos_sum,
                          int R, int C) {
    int gid  = blockIdx.x * blockDim.x + threadIdx.x;
    int wid  = gid >> 6;
    int lane = threadIdx.x & 63;
    int nw   = (gridDim.x * blockDim.x) >> 6;
    double acc = 0.0;
    for (int r = wid; r < R; r += nw) {
        const float* base = cls + (size_t)r * C;
        float m = -INFINITY;
        for (int i = lane; i < C; i += 64) m = fmaxf(m, base[i]);
        for (int s = 32; s > 0; s >>= 1) m = fmaxf(m, __shfl_xor(m, s));
        float e = 0.0f;
        for (int i = lane; i < C; i += 64) e += __expf(base[i] - m);
        for (int s = 32; s > 0; s >>= 1) e += __shfl_xor(e, s);
        int tgt = tcls[r];
        float lt = base[tgt];
        float ce = fmaxf(__logf(e) + m - lt, 0.0f);
        if (lane == 0) {
            if (tgt != 0) { acc += (double)ce; negbuf[r] = 0.0f; }
            else          { negbuf[r] = ce; }
        }
    }
    if (lane == 0 && acc != 0.0) atomicAdd(pos_sum, acc);
}

// ---------------------------------------------------------------------------
// hardneg: exact top-k sum via byte radix-select, per-wave histogram replicas
// ---------------------------------------------------------------------------
__global__ void hardneg_kernel(const float* __restrict__ neg,
                               const int*   __restrict__ n_pos,
                               double* __restrict__ neg_sum,
                               int D) {
    int b = blockIdx.x, t = threadIdx.x;
    int w = t >> 6;
    const float* row = neg + (size_t)b * D;

    __shared__ unsigned bins[4][256];
    __shared__ unsigned sh_kk, sh_prefix, sh_pmask;
    __shared__ double sred[256];

    if (t == 0) {
        int k = 3 * n_pos[b];
        if (k > D) k = D;
        sh_kk = (unsigned)k; sh_prefix = 0u; sh_pmask = 0u;
    }
    __syncthreads();
    if ((int)sh_kk <= 0) { if (t == 0) {} return; }

    for (int shift = 24; shift >= 0; shift -= 8) {
#pragma unroll
        for (int i = 0; i < 4; ++i) bins[i][t] = 0;
        __syncthreads();
        unsigned pmask = sh_pmask, prefix = sh_prefix;
        for (int i = t; i < D; i += 256) {
            unsigned v = __float_as_uint(row[i]);
            if ((v & pmask) == prefix) atomicAdd(&bins[w][(v >> shift) & 255u], 1u);
        }
        __syncthreads();
        bins[0][t] += bins[1][t] + bins[2][t] + bins[3][t];
        __syncthreads();
        if (t == 0) {
            unsigned kk = sh_kk, cum = 0; int sel = 0;
            for (int bb = 255; bb >= 0; --bb) {
                unsigned c = bins[0][bb];
                if (cum + c >= kk) { sel = bb; break; }
                cum += c;
            }
            sh_kk = kk - cum;
            sh_prefix = prefix | ((unsigned)sel << shift);
            sh_pmask = pmask | (255u << shift);
        }
        __syncthreads();
    }
    unsigned T = sh_prefix, kk_rem = sh_kk;

    double local = 0.0;
    for (int i = t; i < D; i += 256) {
        unsigned v = __float_as_uint(row[i]);
        if (v > T) local += (double)row[i];
    }
    sred[t] = local;
    __syncthreads();
    for (int s = 128; s > 0; s >>= 1) {
        if (t < s) sred[t] += sred[t + s];
        __syncthreads();
    }
    if (t == 0) {
        double tot = sred[0] + (double)kk_rem * (double)__uint_as_float(T);
        atomicAdd(neg_sum, tot);
    }
}

// ---------------------------------------------------------------------------
__global__ void finalize_kernel(const double* __restrict__ loc_sum,
                                const double* __restrict__ pos_sum,
                                const double* __restrict__ neg_sum,
                                const int*    __restrict__ npt,
                                float* __restrict__ out) {
    double n = (double)(*npt);
    out[0] = (float)((*loc_sum) / (n * 4.0));
    out[1] = (float)(((*neg_sum) + (*pos_sum)) / n);
}

// ---------------------------------------------------------------------------
extern "C" void kernel_launch(void* const* d_in, const int* in_sizes, int n_in,
                              void* d_out, int out_size, void* d_ws, size_t ws_size,
                              hipStream_t stream) {
    const float* locs   = (const float*)d_in[0];
    const float* cls    = (const float*)d_in[1];
    const float* boxes  = (const float*)d_in[2];
    const int*   labels = (const int*)d_in[3];
    const float* dboxes = (const float*)d_in[4];

    int D = in_sizes[4] / 4;
    int B = in_sizes[0] / (4 * D);
    int O = in_sizes[3] / B;
    int C = in_sizes[1] / (B * D);
    int R = B * D;

    char* ws = (char*)d_ws;
    double* loc_sum = (double*)ws;                    // [0,8)
    double* pos_sum = loc_sum + 1;                    // [8,16)
    double* neg_sum = loc_sum + 2;                    // [16,24)
    int*    npt     = (int*)(ws + 24);                // [24,28)
    unsigned long long* key64 = (unsigned long long*)(ws + 32); // [32, 32+B*O*8)
    size_t off = 32 + (size_t)B * O * 8;
    int* n_pos = (int*)(ws + off); off += (size_t)B * 4;
    size_t zero_bytes = off;
    off = (off + 15) & ~(size_t)15;
    int*   tcls   = (int*)(ws + off); off += (size_t)R * 4;
    float* negbuf = (float*)(ws + off);

    hipMemsetAsync(d_ws, 0, zero_bytes, stream);

    const int chunk = 1024;
    int CH1 = (D + chunk - 1) / chunk;
    m1_kernel<<<B * CH1, 256, 0, stream>>>(boxes, dboxes, tcls, (float*)negbuf /*reuse as ovl*/,
                                           key64, D, O, CH1, chunk);
    m2_kernel<<<1, 256, 0, stream>>>(key64, tcls, negbuf, D, O, B);
    int CHm = (D + 255) / 256;
    m3_kernel<<<B * CHm, 256, 0, stream>>>(boxes, labels, dboxes, locs, tcls, negbuf,
                                           n_pos, loc_sum, npt, D, O, CHm);
    if (C == 81 && (R % 64) == 0) {
        int ntiles = R / 64;
        int grid = ntiles < 1792 ? ntiles : 1792;
        ce_tile_kernel<81><<<grid, 256, 0, stream>>>(cls, tcls, negbuf, pos_sum, R);
    } else {
        ce_kernel<<<2048, 256, 0, stream>>>(cls, tcls, negbuf, pos_sum, R, C);
    }
    hardneg_kernel<<<B, 256, 0, stream>>>(negbuf, n_pos, neg_sum, D);
    finalize_kernel<<<1, 1, 0, stream>>>(loc_sum, pos_sum, neg_sum, npt, (float*)d_out);
}

// Round 3
// 475.501 us; speedup vs baseline: 1.0278x; 1.0278x over previous
//
#include <hip/hip_runtime.h>
#include <hip/hip_bf16.h>
#include <math.h>

#define MAXO 16

// ---------------------------------------------------------------------------
// m1: IoU over (b, d-chunk): per-default argmax over objects (first-wins),
//     per-object argmax over defaults: per-thread -> wave shfl reduce ->
//     cross-wave LDS reduce -> ONE atomicMax per (block, object).
//     key = (iou_bits << 32) | (~d)  -> max iou, tie -> lowest d
// ---------------------------------------------------------------------------
__global__ void m1_kernel(const float* __restrict__ boxes,   // [B,O,4] xy
                          const float* __restrict__ dboxes,  // [D,4] cxcy
                          int*   __restrict__ tcls,          // [B,D] obj idx
                          float* __restrict__ ovl,           // [B,D] best iou
                          unsigned long long* __restrict__ key64, // [B,O]
                          int D, int O, int CH, int chunk) {
    int b = blockIdx.x / CH, c = blockIdx.x % CH;
    int t = threadIdx.x;

    __shared__ float sbox[MAXO][4];
    __shared__ float sarea[MAXO];
    __shared__ unsigned long long skey[4][MAXO];
    if (t < O) {
        const float* bp = boxes + ((size_t)b * O + t) * 4;
        float x1 = bp[0], y1 = bp[1], x2 = bp[2], y2 = bp[3];
        sbox[t][0] = x1; sbox[t][1] = y1; sbox[t][2] = x2; sbox[t][3] = y2;
        sarea[t] = (x2 - x1) * (y2 - y1);
    }
    __syncthreads();

    float bestv[MAXO];
    int   besti[MAXO];
#pragma unroll
    for (int o = 0; o < MAXO; ++o) { bestv[o] = -1.0f; besti[o] = 0x7fffffff; }

    size_t rowoff = (size_t)b * D;
    int d0 = c * chunk, d1 = min(D, d0 + chunk);

    for (int d = d0 + t; d < d1; d += 256) {
        float4 db = ((const float4*)dboxes)[d];
        float dx1 = db.x - db.z * 0.5f, dy1 = db.y - db.w * 0.5f;
        float dx2 = db.x + db.z * 0.5f, dy2 = db.y + db.w * 0.5f;
        float a2 = (dx2 - dx1) * (dy2 - dy1);
        float mval = -1.0f; int mobj = 0;
#pragma unroll
        for (int o = 0; o < MAXO; ++o) {
            if (o < O) {
                float lx = fmaxf(sbox[o][0], dx1), ly = fmaxf(sbox[o][1], dy1);
                float rx = fminf(sbox[o][2], dx2), ry = fminf(sbox[o][3], dy2);
                float w = fmaxf(rx - lx, 0.0f), h = fmaxf(ry - ly, 0.0f);
                float inter = w * h;
                float iou = inter / (sarea[o] + a2 - inter);
                if (iou > mval) { mval = iou; mobj = o; }   // first-wins over o
                if (iou > bestv[o] || (iou == bestv[o] && d < besti[o])) {
                    bestv[o] = iou; besti[o] = d;           // lowest-d wins
                }
            }
        }
        tcls[rowoff + d] = mobj;
        ovl[rowoff + d]  = mval;
    }

    // block-local reduction of packed keys (iou>=0 always; -1 sentinel -> 0)
    int w = t >> 6;
#pragma unroll
    for (int o = 0; o < MAXO; ++o) {
        if (o < O) {
            unsigned long long k = (bestv[o] >= 0.0f)
                ? (((unsigned long long)__float_as_uint(bestv[o]) << 32) |
                   (unsigned long long)(0xFFFFFFFFu - (unsigned)besti[o]))
                : 0ull;
            for (int s = 32; s > 0; s >>= 1) {
                unsigned long long k2 =
                    (unsigned long long)__shfl_xor((long long)k, s);
                if (k2 > k) k = k2;
            }
            if ((t & 63) == 0) skey[w][o] = k;
        }
    }
    __syncthreads();
    if (t < O) {
        unsigned long long k = skey[0][t];
#pragma unroll
        for (int i = 1; i < 4; ++i) {
            unsigned long long k2 = skey[i][t];
            if (k2 > k) k = k2;
        }
        if (k) atomicMax(&key64[(size_t)b * O + t], k);   // 16 atomics per block
    }
}

// ---------------------------------------------------------------------------
// m2: sequential last-write-wins override (numpy scatter semantics)
// ---------------------------------------------------------------------------
__global__ void m2_kernel(const unsigned long long* __restrict__ key64,
                          int* __restrict__ tcls, float* __restrict__ ovl,
                          int D, int O, int B) {
    int b = threadIdx.x;
    if (b >= B) return;
    size_t rowoff = (size_t)b * D;
    for (int o = 0; o < O; ++o) {
        unsigned long long key = key64[(size_t)b * O + o];
        int d = (int)(0xFFFFFFFFu - (unsigned)(key & 0xFFFFFFFFull));
        tcls[rowoff + d] = o;
        ovl[rowoff + d]  = 1.0f;
    }
}

// ---------------------------------------------------------------------------
// m3: labels, encode, smooth-L1 for positives; n_pos / npt / loc_sum
// ---------------------------------------------------------------------------
__global__ void m3_kernel(const float* __restrict__ boxes,
                          const int*   __restrict__ labels,
                          const float* __restrict__ dboxes,
                          const float* __restrict__ locs,
                          int*   __restrict__ tcls,
                          const float* __restrict__ ovl,
                          int*   __restrict__ n_pos,
                          double* __restrict__ loc_sum,
                          int*   __restrict__ npt,
                          int D, int O, int CHm) {
    int b = blockIdx.x / CHm, c = blockIdx.x % CHm;
    int t = threadIdx.x;
    int d = c * 256 + t;

    __shared__ float sbox[MAXO][4];
    __shared__ int   slab[MAXO];
    __shared__ double sred[256];
    __shared__ int    sredi[256];
    if (t < O) {
        const float* bp = boxes + ((size_t)b * O + t) * 4;
        sbox[t][0] = bp[0]; sbox[t][1] = bp[1]; sbox[t][2] = bp[2]; sbox[t][3] = bp[3];
        slab[t] = labels[(size_t)b * O + t];
    }
    __syncthreads();

    double acc = 0.0;
    int cnt = 0;
    if (d < D) {
        size_t rowoff = (size_t)b * D;
        int o = tcls[rowoff + d];
        float ov = ovl[rowoff + d];
        int lab = (ov < 0.5f) ? 0 : slab[o];
        tcls[rowoff + d] = lab;
        if (lab != 0) {
            cnt = 1;
            float x1 = sbox[o][0], y1 = sbox[o][1], x2 = sbox[o][2], y2 = sbox[o][3];
            float cx = (x1 + x2) * 0.5f, cy = (y1 + y2) * 0.5f;
            float w = x2 - x1, h = y2 - y1;
            float4 db = ((const float4*)dboxes)[d];
            float g0 = (cx - db.x) / (db.z * 0.1f);
            float g1 = (cy - db.y) / (db.w * 0.1f);
            float g2 = __logf(w / db.z) * 5.0f;
            float g3 = __logf(h / db.w) * 5.0f;
            float4 lp = ((const float4*)locs)[rowoff + d];
            float dd;
            dd = fabsf(lp.x - g0); acc += (dd < 1.0f) ? 0.5f * dd * dd : dd - 0.5f;
            dd = fabsf(lp.y - g1); acc += (dd < 1.0f) ? 0.5f * dd * dd : dd - 0.5f;
            dd = fabsf(lp.z - g2); acc += (dd < 1.0f) ? 0.5f * dd * dd : dd - 0.5f;
            dd = fabsf(lp.w - g3); acc += (dd < 1.0f) ? 0.5f * dd * dd : dd - 0.5f;
        }
    }
    sred[t] = acc; sredi[t] = cnt;
    __syncthreads();
    for (int s = 128; s > 0; s >>= 1) {
        if (t < s) { sred[t] += sred[t + s]; sredi[t] += sredi[t + s]; }
        __syncthreads();
    }
    if (t == 0) {
        if (sredi[0]) { atomicAdd(&n_pos[b], sredi[0]); atomicAdd(npt, sredi[0]); }
        if (sred[0] != 0.0) atomicAdd(loc_sum, sred[0]);
    }
}

// ---------------------------------------------------------------------------
// ce (fast path, C known at compile time): 64-row LDS tiles, 4 threads/row,
// row elements held in registers, quad shfl reduce, hw transcendentals
// ---------------------------------------------------------------------------
template<int CC>
__global__ __launch_bounds__(256) void ce_tile_kernel(
        const float* __restrict__ cls,  // [R,CC]
        const int*   __restrict__ tcls, // [R]
        float* __restrict__ negbuf,     // [R]
        double* __restrict__ pos_sum,   // [1]
        int R) {
    constexpr int TF  = 64 * CC;      // floats per tile
    constexpr int TF4 = TF / 4;       // float4 per tile
    constexpr int PER = (CC + 3) / 4; // elems per thread
    __shared__ __align__(16) float lds[TF];
    int t = threadIdx.x;
    int ntiles = R / 64;
    double acc = 0.0;

    for (int tile = blockIdx.x; tile < ntiles; tile += gridDim.x) {
        const float4* g4 = (const float4*)cls + (size_t)tile * TF4;
#pragma unroll
        for (int i = 0; i < (TF4 + 255) / 256; ++i) {
            int idx = t + i * 256;
            if (idx < TF4) ((float4*)lds)[idx] = g4[idx];
        }
        __syncthreads();

        int rr = t >> 2, p = t & 3;
        int row = tile * 64 + rr;
        const float* Lr = lds + rr * CC;
        int j0 = p * PER;

        float v[PER];
#pragma unroll
        for (int k = 0; k < PER; ++k) {
            int j = j0 + k;
            v[k] = (j < CC) ? Lr[j] : -INFINITY;
        }
        float m = v[0];
#pragma unroll
        for (int k = 1; k < PER; ++k) m = fmaxf(m, v[k]);
        m = fmaxf(m, __shfl_xor(m, 1));
        m = fmaxf(m, __shfl_xor(m, 2));
        float e = 0.0f;
#pragma unroll
        for (int k = 0; k < PER; ++k) e += __expf(v[k] - m); // exp(-inf)=0
        e += __shfl_xor(e, 1);
        e += __shfl_xor(e, 2);

        if (p == 0) {
            int tgt = tcls[row];
            float lt = Lr[tgt];
            float ce = __logf(e) + m - lt;
            ce = fmaxf(ce, 0.0f);
            if (tgt != 0) acc += (double)ce;
            negbuf[row] = (tgt != 0) ? 0.0f : ce;
        }
        __syncthreads();
    }

    // block-reduce acc -> one atomic
    double* sd = (double*)lds;
    sd[t] = acc;
    __syncthreads();
    for (int s = 128; s > 0; s >>= 1) {
        if (t < s) sd[t] += sd[t + s];
        __syncthreads();
    }
    if (t == 0 && sd[0] != 0.0) atomicAdd(pos_sum, sd[0]);
}

// ---------------------------------------------------------------------------
// ce fallback (generic C): wave per row
// ---------------------------------------------------------------------------
__global__ void ce_kernel(const float* __restrict__ cls, const int* __restrict__ tcls,
                          float* __restrict__ negbuf, double* __restrict__ pos_sum,
                          int R, int C) {
    int gid  = blockIdx.x * blockDim.x + threadIdx.x;
    int wid  = gid >> 6;
    int lane = threadIdx.x & 63;
    int nw   = (gridDim.x * blockDim.x) >> 6;
    double acc = 0.0;
    for (int r = wid; r < R; r += nw) {
        const float* base = cls + (size_t)r * C;
        float m = -INFINITY;
        for (int i = lane; i < C; i += 64) m = fmaxf(m, base[i]);
        for (int s = 32; s > 0; s >>= 1) m = fmaxf(m, __shfl_xor(m, s));
        float e = 0.0f;
        for (int i = lane; i < C; i += 64) e += __expf(base[i] - m);
        for (int s = 32; s > 0; s >>= 1) e += __shfl_xor(e, s);
        int tgt = tcls[r];
        float lt = base[tgt];
        float ce = fmaxf(__logf(e) + m - lt, 0.0f);
        if (lane == 0) {
            if (tgt != 0) { acc += (double)ce; negbuf[r] = 0.0f; }
            else          { negbuf[r] = ce; }
        }
    }
    if (lane == 0 && acc != 0.0) atomicAdd(pos_sum, acc);
}

// ---------------------------------------------------------------------------
// hardneg: exact top-k sum via byte radix-select, per-wave histogram replicas
// ---------------------------------------------------------------------------
__global__ void hardneg_kernel(const float* __restrict__ neg,
                               const int*   __restrict__ n_pos,
                               double* __restrict__ neg_sum,
                               int D) {
    int b = blockIdx.x, t = threadIdx.x;
    int w = t >> 6;
    const float* row = neg + (size_t)b * D;

    __shared__ unsigned bins[4][256];
    __shared__ unsigned sh_kk, sh_prefix, sh_pmask;
    __shared__ double sred[256];

    if (t == 0) {
        int k = 3 * n_pos[b];
        if (k > D) k = D;
        sh_kk = (unsigned)k; sh_prefix = 0u; sh_pmask = 0u;
    }
    __syncthreads();
    if ((int)sh_kk <= 0) return;

    for (int shift = 24; shift >= 0; shift -= 8) {
#pragma unroll
        for (int i = 0; i < 4; ++i) bins[i][t] = 0;
        __syncthreads();
        unsigned pmask = sh_pmask, prefix = sh_prefix;
        for (int i = t; i < D; i += 256) {
            unsigned v = __float_as_uint(row[i]);
            if ((v & pmask) == prefix) atomicAdd(&bins[w][(v >> shift) & 255u], 1u);
        }
        __syncthreads();
        bins[0][t] += bins[1][t] + bins[2][t] + bins[3][t];
        __syncthreads();
        if (t == 0) {
            unsigned kk = sh_kk, cum = 0; int sel = 0;
            for (int bb = 255; bb >= 0; --bb) {
                unsigned c = bins[0][bb];
                if (cum + c >= kk) { sel = bb; break; }
                cum += c;
            }
            sh_kk = kk - cum;
            sh_prefix = prefix | ((unsigned)sel << shift);
            sh_pmask = pmask | (255u << shift);
        }
        __syncthreads();
    }
    unsigned T = sh_prefix, kk_rem = sh_kk;

    double local = 0.0;
    for (int i = t; i < D; i += 256) {
        unsigned v = __float_as_uint(row[i]);
        if (v > T) local += (double)row[i];
    }
    sred[t] = local;
    __syncthreads();
    for (int s = 128; s > 0; s >>= 1) {
        if (t < s) sred[t] += sred[t + s];
        __syncthreads();
    }
    if (t == 0) {
        double tot = sred[0] + (double)kk_rem * (double)__uint_as_float(T);
        atomicAdd(neg_sum, tot);
    }
}

// ---------------------------------------------------------------------------
__global__ void finalize_kernel(const double* __restrict__ loc_sum,
                                const double* __restrict__ pos_sum,
                                const double* __restrict__ neg_sum,
                                const int*    __restrict__ npt,
                                float* __restrict__ out) {
    double n = (double)(*npt);
    out[0] = (float)((*loc_sum) / (n * 4.0));
    out[1] = (float)(((*neg_sum) + (*pos_sum)) / n);
}

// ---------------------------------------------------------------------------
extern "C" void kernel_launch(void* const* d_in, const int* in_sizes, int n_in,
                              void* d_out, int out_size, void* d_ws, size_t ws_size,
                              hipStream_t stream) {
    const float* locs   = (const float*)d_in[0];
    const float* cls    = (const float*)d_in[1];
    const float* boxes  = (const float*)d_in[2];
    const int*   labels = (const int*)d_in[3];
    const float* dboxes = (const float*)d_in[4];

    int D = in_sizes[4] / 4;
    int B = in_sizes[0] / (4 * D);
    int O = in_sizes[3] / B;
    int C = in_sizes[1] / (B * D);
    int R = B * D;

    char* ws = (char*)d_ws;
    double* loc_sum = (double*)ws;                    // [0,8)
    double* pos_sum = loc_sum + 1;                    // [8,16)
    double* neg_sum = loc_sum + 2;                    // [16,24)
    int*    npt     = (int*)(ws + 24);                // [24,28)
    unsigned long long* key64 = (unsigned long long*)(ws + 32); // [32, 32+B*O*8)
    size_t off = 32 + (size_t)B * O * 8;
    int* n_pos = (int*)(ws + off); off += (size_t)B * 4;
    size_t zero_bytes = off;
    off = (off + 15) & ~(size_t)15;
    int*   tcls   = (int*)(ws + off); off += (size_t)R * 4;
    float* negbuf = (float*)(ws + off);

    hipMemsetAsync(d_ws, 0, zero_bytes, stream);

    const int chunk = 1024;
    int CH1 = (D + chunk - 1) / chunk;
    m1_kernel<<<B * CH1, 256, 0, stream>>>(boxes, dboxes, tcls, (float*)negbuf /*reuse as ovl*/,
                                           key64, D, O, CH1, chunk);
    m2_kernel<<<1, 256, 0, stream>>>(key64, tcls, negbuf, D, O, B);
    int CHm = (D + 255) / 256;
    m3_kernel<<<B * CHm, 256, 0, stream>>>(boxes, labels, dboxes, locs, tcls, negbuf,
                                           n_pos, loc_sum, npt, D, O, CHm);
    if (C == 81 && (R % 64) == 0) {
        int ntiles = R / 64;
        int grid = ntiles < 1792 ? ntiles : 1792;
        ce_tile_kernel<81><<<grid, 256, 0, stream>>>(cls, tcls, negbuf, pos_sum, R);
    } else {
        ce_kernel<<<2048, 256, 0, stream>>>(cls, tcls, negbuf, pos_sum, R, C);
    }
    hardneg_kernel<<<B, 256, 0, stream>>>(negbuf, n_pos, neg_sum, D);
    finalize_kernel<<<1, 1, 0, stream>>>(loc_sum, pos_sum, neg_sum, npt, (float*)d_out);
}

// Round 4
// 206.686 us; speedup vs baseline: 2.3646x; 2.3006x over previous
//
#include <hip/hip_runtime.h>
#include <hip/hip_bf16.h>
#include <math.h>

#define MAXO 16

// ---------------------------------------------------------------------------
// m1: IoU over (b, d-chunk): per-default argmax over objects (first-wins),
//     per-object argmax over defaults via packed 64-bit keys kept in REGISTERS
//     (launch_bounds raises VGPR budget -> no scratch spill), then wave shfl
//     reduce -> cross-wave LDS -> ONE atomicMax per (block, object).
//     key = (iou_bits << 32) | (~d)  -> max iou, tie -> lowest d
// ---------------------------------------------------------------------------
__global__ __launch_bounds__(256, 2)
void m1_kernel(const float* __restrict__ boxes,   // [B,O,4] xy
               const float* __restrict__ dboxes,  // [D,4] cxcy
               int*   __restrict__ tcls,          // [B,D] obj idx
               float* __restrict__ ovl,           // [B,D] best iou
               unsigned long long* __restrict__ key64, // [B,O]
               int D, int O, int CH, int chunk) {
    int b = blockIdx.x / CH, c = blockIdx.x % CH;
    int t = threadIdx.x;

    __shared__ float sbox[MAXO][4];
    __shared__ float sarea[MAXO];
    __shared__ unsigned long long skey[4][MAXO];
    if (t < O) {
        const float* bp = boxes + ((size_t)b * O + t) * 4;
        float x1 = bp[0], y1 = bp[1], x2 = bp[2], y2 = bp[3];
        sbox[t][0] = x1; sbox[t][1] = y1; sbox[t][2] = x2; sbox[t][3] = y2;
        sarea[t] = (x2 - x1) * (y2 - y1);
    }
    __syncthreads();

    unsigned long long bestk[MAXO];
#pragma unroll
    for (int o = 0; o < MAXO; ++o) bestk[o] = 0ull;

    size_t rowoff = (size_t)b * D;
    int d0 = c * chunk, d1 = min(D, d0 + chunk);

    for (int d = d0 + t; d < d1; d += 256) {
        float4 db = ((const float4*)dboxes)[d];
        float dx1 = db.x - db.z * 0.5f, dy1 = db.y - db.w * 0.5f;
        float dx2 = db.x + db.z * 0.5f, dy2 = db.y + db.w * 0.5f;
        float a2 = (dx2 - dx1) * (dy2 - dy1);
        unsigned notd = 0xFFFFFFFFu - (unsigned)d;
        float mval = -1.0f; int mobj = 0;
#pragma unroll
        for (int o = 0; o < MAXO; ++o) {
            if (o < O) {
                float lx = fmaxf(sbox[o][0], dx1), ly = fmaxf(sbox[o][1], dy1);
                float rx = fminf(sbox[o][2], dx2), ry = fminf(sbox[o][3], dy2);
                float w = fmaxf(rx - lx, 0.0f), h = fmaxf(ry - ly, 0.0f);
                float inter = w * h;
                float iou = inter / (sarea[o] + a2 - inter);
                if (iou > mval) { mval = iou; mobj = o; }   // first-wins over o
                unsigned long long key =
                    ((unsigned long long)__float_as_uint(iou) << 32) |
                    (unsigned long long)notd;               // max iou, lowest d
                if (key > bestk[o]) bestk[o] = key;
            }
        }
        tcls[rowoff + d] = mobj;
        ovl[rowoff + d]  = mval;
    }

    // block-local reduction of packed keys
    int w = t >> 6;
#pragma unroll
    for (int o = 0; o < MAXO; ++o) {
        if (o < O) {
            unsigned long long k = bestk[o];
            for (int s = 32; s > 0; s >>= 1) {
                unsigned long long k2 =
                    (unsigned long long)__shfl_xor((long long)k, s);
                if (k2 > k) k = k2;
            }
            if ((t & 63) == 0) skey[w][o] = k;
        }
    }
    __syncthreads();
    if (t < O) {
        unsigned long long k = skey[0][t];
#pragma unroll
        for (int i = 1; i < 4; ++i) {
            unsigned long long k2 = skey[i][t];
            if (k2 > k) k = k2;
        }
        if (k) atomicMax(&key64[(size_t)b * O + t], k);   // 16 atomics per block
    }
}

// ---------------------------------------------------------------------------
// m2: sequential last-write-wins override (numpy scatter semantics)
// ---------------------------------------------------------------------------
__global__ void m2_kernel(const unsigned long long* __restrict__ key64,
                          int* __restrict__ tcls, float* __restrict__ ovl,
                          int D, int O, int B) {
    int b = threadIdx.x;
    if (b >= B) return;
    size_t rowoff = (size_t)b * D;
    for (int o = 0; o < O; ++o) {
        unsigned long long key = key64[(size_t)b * O + o];
        int d = (int)(0xFFFFFFFFu - (unsigned)(key & 0xFFFFFFFFull));
        tcls[rowoff + d] = o;
        ovl[rowoff + d]  = 1.0f;
    }
}

// ---------------------------------------------------------------------------
// m3: labels, encode, smooth-L1 for positives; n_pos / npt / loc_sum
// ---------------------------------------------------------------------------
__global__ void m3_kernel(const float* __restrict__ boxes,
                          const int*   __restrict__ labels,
                          const float* __restrict__ dboxes,
                          const float* __restrict__ locs,
                          int*   __restrict__ tcls,
                          const float* __restrict__ ovl,
                          int*   __restrict__ n_pos,
                          double* __restrict__ loc_sum,
                          int*   __restrict__ npt,
                          int D, int O, int CHm) {
    int b = blockIdx.x / CHm, c = blockIdx.x % CHm;
    int t = threadIdx.x;
    int d = c * 256 + t;

    __shared__ float sbox[MAXO][4];
    __shared__ int   slab[MAXO];
    __shared__ double sred[256];
    __shared__ int    sredi[256];
    if (t < O) {
        const float* bp = boxes + ((size_t)b * O + t) * 4;
        sbox[t][0] = bp[0]; sbox[t][1] = bp[1]; sbox[t][2] = bp[2]; sbox[t][3] = bp[3];
        slab[t] = labels[(size_t)b * O + t];
    }
    __syncthreads();

    double acc = 0.0;
    int cnt = 0;
    if (d < D) {
        size_t rowoff = (size_t)b * D;
        int o = tcls[rowoff + d];
        float ov = ovl[rowoff + d];
        int lab = (ov < 0.5f) ? 0 : slab[o];
        tcls[rowoff + d] = lab;
        if (lab != 0) {
            cnt = 1;
            float x1 = sbox[o][0], y1 = sbox[o][1], x2 = sbox[o][2], y2 = sbox[o][3];
            float cx = (x1 + x2) * 0.5f, cy = (y1 + y2) * 0.5f;
            float w = x2 - x1, h = y2 - y1;
            float4 db = ((const float4*)dboxes)[d];
            float g0 = (cx - db.x) / (db.z * 0.1f);
            float g1 = (cy - db.y) / (db.w * 0.1f);
            float g2 = __logf(w / db.z) * 5.0f;
            float g3 = __logf(h / db.w) * 5.0f;
            float4 lp = ((const float4*)locs)[rowoff + d];
            float dd;
            dd = fabsf(lp.x - g0); acc += (dd < 1.0f) ? 0.5f * dd * dd : dd - 0.5f;
            dd = fabsf(lp.y - g1); acc += (dd < 1.0f) ? 0.5f * dd * dd : dd - 0.5f;
            dd = fabsf(lp.z - g2); acc += (dd < 1.0f) ? 0.5f * dd * dd : dd - 0.5f;
            dd = fabsf(lp.w - g3); acc += (dd < 1.0f) ? 0.5f * dd * dd : dd - 0.5f;
        }
    }
    sred[t] = acc; sredi[t] = cnt;
    __syncthreads();
    for (int s = 128; s > 0; s >>= 1) {
        if (t < s) { sred[t] += sred[t + s]; sredi[t] += sredi[t + s]; }
        __syncthreads();
    }
    if (t == 0) {
        if (sredi[0]) { atomicAdd(&n_pos[b], sredi[0]); atomicAdd(npt, sredi[0]); }
        if (sred[0] != 0.0) atomicAdd(loc_sum, sred[0]);
    }
}

// ---------------------------------------------------------------------------
// ce (fast path, C known at compile time): 64-row LDS tiles, 4 threads/row,
// row elements held in registers, quad shfl reduce, hw transcendentals
// ---------------------------------------------------------------------------
template<int CC>
__global__ __launch_bounds__(256) void ce_tile_kernel(
        const float* __restrict__ cls,  // [R,CC]
        const int*   __restrict__ tcls, // [R]
        float* __restrict__ negbuf,     // [R]
        double* __restrict__ pos_sum,   // [1]
        int R) {
    constexpr int TF  = 64 * CC;      // floats per tile
    constexpr int TF4 = TF / 4;       // float4 per tile
    constexpr int PER = (CC + 3) / 4; // elems per thread
    __shared__ __align__(16) float lds[TF];
    int t = threadIdx.x;
    int ntiles = R / 64;
    double acc = 0.0;

    for (int tile = blockIdx.x; tile < ntiles; tile += gridDim.x) {
        const float4* g4 = (const float4*)cls + (size_t)tile * TF4;
#pragma unroll
        for (int i = 0; i < (TF4 + 255) / 256; ++i) {
            int idx = t + i * 256;
            if (idx < TF4) ((float4*)lds)[idx] = g4[idx];
        }
        __syncthreads();

        int rr = t >> 2, p = t & 3;
        int row = tile * 64 + rr;
        const float* Lr = lds + rr * CC;
        int j0 = p * PER;

        float v[PER];
#pragma unroll
        for (int k = 0; k < PER; ++k) {
            int j = j0 + k;
            v[k] = (j < CC) ? Lr[j] : -INFINITY;
        }
        float m = v[0];
#pragma unroll
        for (int k = 1; k < PER; ++k) m = fmaxf(m, v[k]);
        m = fmaxf(m, __shfl_xor(m, 1));
        m = fmaxf(m, __shfl_xor(m, 2));
        float e = 0.0f;
#pragma unroll
        for (int k = 0; k < PER; ++k) e += __expf(v[k] - m); // exp(-inf)=0
        e += __shfl_xor(e, 1);
        e += __shfl_xor(e, 2);

        if (p == 0) {
            int tgt = tcls[row];
            float lt = Lr[tgt];
            float ce = __logf(e) + m - lt;
            ce = fmaxf(ce, 0.0f);
            if (tgt != 0) acc += (double)ce;
            negbuf[row] = (tgt != 0) ? 0.0f : ce;
        }
        __syncthreads();
    }

    // block-reduce acc -> one atomic
    double* sd = (double*)lds;
    sd[t] = acc;
    __syncthreads();
    for (int s = 128; s > 0; s >>= 1) {
        if (t < s) sd[t] += sd[t + s];
        __syncthreads();
    }
    if (t == 0 && sd[0] != 0.0) atomicAdd(pos_sum, sd[0]);
}

// ---------------------------------------------------------------------------
// ce fallback (generic C): wave per row
// ---------------------------------------------------------------------------
__global__ void ce_kernel(const float* __restrict__ cls, const int* __restrict__ tcls,
                          float* __restrict__ negbuf, double* __restrict__ pos_sum,
                          int R, int C) {
    int gid  = blockIdx.x * blockDim.x + threadIdx.x;
    int wid  = gid >> 6;
    int lane = threadIdx.x & 63;
    int nw   = (gridDim.x * blockDim.x) >> 6;
    double acc = 0.0;
    for (int r = wid; r < R; r += nw) {
        const float* base = cls + (size_t)r * C;
        float m = -INFINITY;
        for (int i = lane; i < C; i += 64) m = fmaxf(m, base[i]);
        for (int s = 32; s > 0; s >>= 1) m = fmaxf(m, __shfl_xor(m, s));
        float e = 0.0f;
        for (int i = lane; i < C; i += 64) e += __expf(base[i] - m);
        for (int s = 32; s > 0; s >>= 1) e += __shfl_xor(e, s);
        int tgt = tcls[r];
        float lt = base[tgt];
        float ce = fmaxf(__logf(e) + m - lt, 0.0f);
        if (lane == 0) {
            if (tgt != 0) { acc += (double)ce; negbuf[r] = 0.0f; }
            else          { negbuf[r] = ce; }
        }
    }
    if (lane == 0 && acc != 0.0) atomicAdd(pos_sum, acc);
}

// ---------------------------------------------------------------------------
// hardneg: exact top-k sum via byte radix-select, per-wave histogram replicas
// ---------------------------------------------------------------------------
__global__ void hardneg_kernel(const float* __restrict__ neg,
                               const int*   __restrict__ n_pos,
                               double* __restrict__ neg_sum,
                               int D) {
    int b = blockIdx.x, t = threadIdx.x;
    int w = t >> 6;
    const float* row = neg + (size_t)b * D;

    __shared__ unsigned bins[4][256];
    __shared__ unsigned sh_kk, sh_prefix, sh_pmask;
    __shared__ double sred[256];

    if (t == 0) {
        int k = 3 * n_pos[b];
        if (k > D) k = D;
        sh_kk = (unsigned)k; sh_prefix = 0u; sh_pmask = 0u;
    }
    __syncthreads();
    if ((int)sh_kk <= 0) return;

    for (int shift = 24; shift >= 0; shift -= 8) {
#pragma unroll
        for (int i = 0; i < 4; ++i) bins[i][t] = 0;
        __syncthreads();
        unsigned pmask = sh_pmask, prefix = sh_prefix;
        for (int i = t; i < D; i += 256) {
            unsigned v = __float_as_uint(row[i]);
            if ((v & pmask) == prefix) atomicAdd(&bins[w][(v >> shift) & 255u], 1u);
        }
        __syncthreads();
        bins[0][t] += bins[1][t] + bins[2][t] + bins[3][t];
        __syncthreads();
        if (t == 0) {
            unsigned kk = sh_kk, cum = 0; int sel = 0;
            for (int bb = 255; bb >= 0; --bb) {
                unsigned c = bins[0][bb];
                if (cum + c >= kk) { sel = bb; break; }
                cum += c;
            }
            sh_kk = kk - cum;
            sh_prefix = prefix | ((unsigned)sel << shift);
            sh_pmask = pmask | (255u << shift);
        }
        __syncthreads();
    }
    unsigned T = sh_prefix, kk_rem = sh_kk;

    double local = 0.0;
    for (int i = t; i < D; i += 256) {
        unsigned v = __float_as_uint(row[i]);
        if (v > T) local += (double)row[i];
    }
    sred[t] = local;
    __syncthreads();
    for (int s = 128; s > 0; s >>= 1) {
        if (t < s) sred[t] += sred[t + s];
        __syncthreads();
    }
    if (t == 0) {
        double tot = sred[0] + (double)kk_rem * (double)__uint_as_float(T);
        atomicAdd(neg_sum, tot);
    }
}

// ---------------------------------------------------------------------------
__global__ void finalize_kernel(const double* __restrict__ loc_sum,
                                const double* __restrict__ pos_sum,
                                const double* __restrict__ neg_sum,
                                const int*    __restrict__ npt,
                                float* __restrict__ out) {
    double n = (double)(*npt);
    out[0] = (float)((*loc_sum) / (n * 4.0));
    out[1] = (float)(((*neg_sum) + (*pos_sum)) / n);
}

// ---------------------------------------------------------------------------
extern "C" void kernel_launch(void* const* d_in, const int* in_sizes, int n_in,
                              void* d_out, int out_size, void* d_ws, size_t ws_size,
                              hipStream_t stream) {
    const float* locs   = (const float*)d_in[0];
    const float* cls    = (const float*)d_in[1];
    const float* boxes  = (const float*)d_in[2];
    const int*   labels = (const int*)d_in[3];
    const float* dboxes = (const float*)d_in[4];

    int D = in_sizes[4] / 4;
    int B = in_sizes[0] / (4 * D);
    int O = in_sizes[3] / B;
    int C = in_sizes[1] / (B * D);
    int R = B * D;

    char* ws = (char*)d_ws;
    double* loc_sum = (double*)ws;                    // [0,8)
    double* pos_sum = loc_sum + 1;                    // [8,16)
    double* neg_sum = loc_sum + 2;                    // [16,24)
    int*    npt     = (int*)(ws + 24);                // [24,28)
    unsigned long long* key64 = (unsigned long long*)(ws + 32); // [32, 32+B*O*8)
    size_t off = 32 + (size_t)B * O * 8;
    int* n_pos = (int*)(ws + off); off += (size_t)B * 4;
    size_t zero_bytes = off;
    off = (off + 15) & ~(size_t)15;
    int*   tcls   = (int*)(ws + off); off += (size_t)R * 4;
    float* negbuf = (float*)(ws + off);

    hipMemsetAsync(d_ws, 0, zero_bytes, stream);

    const int chunk = 1024;
    int CH1 = (D + chunk - 1) / chunk;
    m1_kernel<<<B * CH1, 256, 0, stream>>>(boxes, dboxes, tcls, (float*)negbuf /*reuse as ovl*/,
                                           key64, D, O, CH1, chunk);
    m2_kernel<<<1, 256, 0, stream>>>(key64, tcls, negbuf, D, O, B);
    int CHm = (D + 255) / 256;
    m3_kernel<<<B * CHm, 256, 0, stream>>>(boxes, labels, dboxes, locs, tcls, negbuf,
                                           n_pos, loc_sum, npt, D, O, CHm);
    if (C == 81 && (R % 64) == 0) {
        int ntiles = R / 64;
        int grid = ntiles < 1792 ? ntiles : 1792;
        ce_tile_kernel<81><<<grid, 256, 0, stream>>>(cls, tcls, negbuf, pos_sum, R);
    } else {
        ce_kernel<<<2048, 256, 0, stream>>>(cls, tcls, negbuf, pos_sum, R, C);
    }
    hardneg_kernel<<<B, 256, 0, stream>>>(negbuf, n_pos, neg_sum, D);
    finalize_kernel<<<1, 1, 0, stream>>>(loc_sum, pos_sum, neg_sum, npt, (float*)d_out);
}